// Round 9
// baseline (1265.626 us; speedup 1.0000x reference)
//
#include <hip/hip_runtime.h>
#include <hip/hip_bf16.h>

typedef unsigned short u16;
typedef unsigned char uchar;
typedef unsigned long long u64;
typedef float f32x4 __attribute__((ext_vector_type(4)));
typedef int i8v __attribute__((ext_vector_type(8)));

#define FDIM 2048
#define NBLK 256
#define NCELL 126

__device__ __forceinline__ u16 f2b(float x) {
    __hip_bfloat16 h = __float2bfloat16(x);
    return __builtin_bit_cast(u16, h);
}
__device__ __forceinline__ float b2f(u16 u) {
    __hip_bfloat16 h = __builtin_bit_cast(__hip_bfloat16, u);
    return __bfloat162float(h);
}
__device__ __forceinline__ float sigm(float x) { return 1.0f / (1.0f + __expf(-x)); }
__device__ __forceinline__ float tanh_f(float x) { return 1.0f - 2.0f / (__expf(2.0f * x) + 1.0f); }

// OCP e4m3 encode (RNE), saturate to 448.
__device__ __forceinline__ unsigned f2fp8(float x) {
    unsigned u = __builtin_bit_cast(unsigned, x);
    unsigned s = (u >> 24) & 0x80u;
    unsigned mag = u & 0x7fffffffu;
    if (mag >= 0x43E80000u) return s | 0x7Eu;
    int e = (int)(mag >> 23) - 127;
    if (e >= -6) {
        unsigned m = mag + 0x7FFFFu + ((mag >> 20) & 1u);
        unsigned e8 = (m >> 23) - 127 + 7;
        unsigned m3 = (m >> 20) & 7u;
        if (e8 >= 16u) return s | 0x7Eu;
        return s | (e8 << 3) | m3;
    }
    float ax = __builtin_bit_cast(float, mag);
    int d = (int)__builtin_rintf(ax * 512.0f);
    return s | (unsigned)d;
}

// e2m1 (fp4) quantize of v (|v|<=6 after scaling): returns 4-bit code
__device__ __forceinline__ unsigned q_e2m1(float v) {
    unsigned s = (v < 0.f) ? 8u : 0u;
    float a = fabsf(v);
    unsigned q;
    if (a < 0.25f) q = 0;
    else if (a < 0.75f) q = 1;
    else if (a < 1.25f) q = 2;
    else if (a < 1.75f) q = 3;
    else if (a < 2.5f)  q = 4;
    else if (a < 3.5f)  q = 5;
    else if (a < 5.0f)  q = 6;
    else q = 7;
    return s | q;
}

// ---------------- weight pack: fp32 -> MX fp4 (E8M0 per-32 scales), MFMA fragment order ----------
__global__ __launch_bounds__(256) void k_pack4(const float* __restrict__ W0, const float* __restrict__ W1,
                                               const float* __restrict__ W2, const float* __restrict__ W3,
                                               uchar* __restrict__ Wp4, uchar* __restrict__ scl) {
    __shared__ float lw[32][132];
    int idx = blockIdx.x;                 // [0, 256*4*16)
    int kt = idx & 15, mat = (idx >> 4) & 3, bl = idx >> 6;
    const float* src = mat == 0 ? W0 : mat == 1 ? W1 : mat == 2 ? W2 : W3;
    int tid = threadIdx.x;
    for (int i = tid; i < 32 * 32; i += 256) {
        int r = i >> 5, c4 = i & 31;
        const float* p = src + (size_t)((r >> 3) * 2048 + bl * 8 + (r & 7)) * 2048 + kt * 128 + c4 * 4;
        float4 v = *(const float4*)p;
        lw[r][c4 * 4 + 0] = v.x; lw[r][c4 * 4 + 1] = v.y;
        lw[r][c4 * 4 + 2] = v.z; lw[r][c4 * 4 + 3] = v.w;
    }
    __syncthreads();
    if (tid < 128) {
        int gp = tid >> 6, lane = tid & 63;
        int r = (2 * gp + ((lane & 15) >> 3)) * 8 + (lane & 7);
        int k0 = (lane >> 4) * 32;
        float mx = 0.f;
#pragma unroll
        for (int e = 0; e < 32; ++e) mx = fmaxf(mx, fabsf(lw[r][k0 + e]));
        int ee = -127;
        if (mx > 0.f) {
            ee = (int)ceilf(log2f(mx * (1.0f / 6.0f)));
            if (ee < -127) ee = -127;
            if (ee > 127) ee = 127;
        }
        float inv = exp2f((float)(-ee));
        unsigned wd[4];
#pragma unroll
        for (int d = 0; d < 4; ++d) {
            unsigned acc = 0;
#pragma unroll
            for (int bi = 0; bi < 4; ++bi) {
                float v0 = lw[r][k0 + d * 8 + 2 * bi] * inv;
                float v1 = lw[r][k0 + d * 8 + 2 * bi + 1] * inv;
                acc |= (q_e2m1(v0) << (bi * 8)) | (q_e2m1(v1) << (bi * 8 + 4));
            }
            wd[d] = acc;
        }
        size_t wo = (size_t)bl * 131072 + (((size_t)(mat * 2 + gp) * 16 + (size_t)kt) * 64 + lane) * 16;
        *(uint4*)(Wp4 + wo) = make_uint4(wd[0], wd[1], wd[2], wd[3]);
        scl[(((size_t)bl * 4 + mat) * 2 + gp) * 1024 + (size_t)lane * 16 + kt] = (uchar)(ee + 127);
    }
}

__global__ void k_bias(const float* __restrict__ bi0, const float* __restrict__ bh0,
                       const float* __restrict__ bi1, const float* __restrict__ bh1,
                       float* __restrict__ bias0, float* __restrict__ bias1) {
    int i = blockIdx.x * blockDim.x + threadIdx.x;
    if (i < 4 * FDIM) {
        bias0[i] = bi0[i] + bh0[i];
        bias1[i] = bi1[i] + bh1[i];
    }
}

// ---------------- input 1x1 conv -> seq slots in MFMA-FRAGMENT layout, fp8 (x4) ----------------
// slot layout: [kt(16)][lane(64)][32B], k = kt*128 + (lane>>4)*32 + byte, row b = lane&15
__global__ __launch_bounds__(256) void k_seqprep(const float* __restrict__ x,
                                                 const float* __restrict__ w_in,
                                                 const float* __restrict__ b_in,
                                                 uchar* __restrict__ seqb) {
    int h = blockIdx.x >> 4, b = blockIdx.x & 15;
    __shared__ float xs[256][32];
    __shared__ float wl[64][257];
    int tid = threadIdx.x;
    for (int i = tid; i < 256 * 32; i += 256) {
        int c = i >> 5, w = i & 31;
        xs[c][w] = x[(((size_t)b * 256 + c) * 32 + h) * 32 + w];
    }
    for (int i = tid; i < 64 * 256; i += 256) {
        int cb = i >> 8, c = i & 255;
        wl[cb][c] = w_in[i];
    }
    __syncthreads();
    int w = (tid * 8) >> 6, cb0 = (tid * 8) & 63;
    float acc[8];
#pragma unroll
    for (int j = 0; j < 8; ++j) acc[j] = b_in[cb0 + j];
    for (int c = 0; c < 256; ++c) {
        float xv = xs[c][w];
#pragma unroll
        for (int j = 0; j < 8; ++j) acc[j] += xv * wl[cb0 + j][c];
    }
    unsigned lo = 0, hi2 = 0;
#pragma unroll
    for (int j = 0; j < 4; ++j) lo |= f2fp8(acc[j] * 4.0f) << (j * 8);
#pragma unroll
    for (int j = 0; j < 4; ++j) hi2 |= f2fp8(acc[4 + j] * 4.0f) << (j * 8);
    int kt = tid >> 4, kq = (tid >> 2) & 3, e0 = (tid & 3) * 8;
    uchar* dst = seqb + (size_t)h * 32768 + (size_t)kt * 2048 + (size_t)(b + 16 * kq) * 32 + e0;
    *(uint2*)dst = make_uint2(lo, hi2);
}

// ---------------- persistent LSTM: LDS-resident fp4 weights, dedup wave split, tag barrier ------
// 8 waves: m = w>>2 (0=ih matrix, 1=hh matrix), q = w&3 (kt-quarter: kt = 4q..4q+3)
// Each wave computes BOTH j-tiles for its (mat, kt) chunk -> A-loads fully deduplicated.
// Partial sums reduced via LDS float atomics into gbuf[par][jt][16][20].
// Arrival: producer stores its own tag word; wave 0 polls 256 tags (4/lane) -> LDS flag.
__global__ __launch_bounds__(512, 1) void k_lstm(const uchar* __restrict__ Wp4,
                                                 const uchar* __restrict__ scl,
                                                 const float* __restrict__ bias0,
                                                 const float* __restrict__ bias1,
                                                 const uchar* __restrict__ seqb,
                                                 uchar* __restrict__ H0, uchar* __restrict__ H1,
                                                 u16* __restrict__ seqout,
                                                 unsigned* __restrict__ tags) {
    __shared__ uchar wlds[131072];            // [mat*2+jt][kt][lane*16]
    __shared__ float gbuf[2][2][16][20];      // [cell-parity][jt][b][j], pad 20 (2-way banks)
    __shared__ u64 hs_st[16];
    __shared__ unsigned flagLDS;
    const int tid = threadIdx.x, lane = tid & 63, w = tid >> 6;
    const int m = w >> 2, q = w & 3;
    const int bl = blockIdx.x;
    const size_t BF = (size_t)16 * FDIM;

    {
        const uchar* src = Wp4 + (size_t)bl * 131072;
        for (int i = tid; i < 8192; i += 512)
            *(uint4*)(wlds + (size_t)i * 16) = *(const uint4*)(src + (size_t)i * 16);
    }
    // scale words: per (mat 0..3, jt 0..1), word covering kt = 4q..4q+3 (bytes 0..3 -> J=t)
    unsigned scw[4][2];
#pragma unroll
    for (int mt = 0; mt < 4; ++mt)
#pragma unroll
        for (int g = 0; g < 2; ++g)
            scw[mt][g] = *(const unsigned*)(scl + (((size_t)bl * 4 + mt) * 2 + g) * 1024
                                            + (size_t)lane * 16 + q * 4);

    // wave-7 tail state: per-lane 2 (b,f) pairs; b = lane>>2, f = (lane&3)*2 + i
    float bw0[2][4], bw1[2][4];
    float cs0[2] = {0.f, 0.f}, cs1[2] = {0.f, 0.f};
    if (w == 7) {
        const int f0 = (lane & 3) * 2;
#pragma unroll
        for (int i = 0; i < 2; ++i) {
            int col = bl * 8 + f0 + i;
#pragma unroll
            for (int g = 0; g < 4; ++g) {
                bw0[i][g] = bias0[g * FDIM + col];
                bw1[i][g] = bias1[g * FDIM + col];
            }
        }
    }
    for (int i = tid; i < 2 * 2 * 16 * 20; i += 512) ((float*)gbuf)[i] = 0.f;
    if (tid == 0) flagLDS = 0;
    __syncthreads();

    const int b16 = lane & 15, kq = lane >> 4;
    for (int c = 0; c < NCELL; ++c) {
        const int s = c >> 1, isL1 = c & 1, par = c & 1;
        const uchar* xsrc = isL1 ? (H0 + (size_t)(s + 1) * BF)
                          : (s < 32 ? (seqb + (size_t)s * BF) : (H1 + (size_t)s * BF));
        const uchar* hsrc = isL1 ? (H1 + (size_t)s * BF) : (H0 + (size_t)s * BF);
        const uchar* asrc = m ? hsrc : xsrc;
        const bool staticX = (!isL1 && s < 32);

        // ---- waits. flag = number of fully-verified cells. ih needs flag>=c (unless static),
        //      hh needs flag>=c-1. Poller (w0) verifies row c-1 and sets flag=c each cell.
        const bool pollBefore = (w == 0) && (c >= 1) && !staticX;
        const bool pollAfter  = (w == 0) && (c >= 1) && staticX;
        if (pollBefore) {
            const unsigned* trow = tags + (size_t)(c - 1) * 256 + lane * 4;
            for (;;) {
                unsigned v0 = __hip_atomic_load(trow + 0, __ATOMIC_RELAXED, __HIP_MEMORY_SCOPE_AGENT);
                unsigned v1 = __hip_atomic_load(trow + 1, __ATOMIC_RELAXED, __HIP_MEMORY_SCOPE_AGENT);
                unsigned v2 = __hip_atomic_load(trow + 2, __ATOMIC_RELAXED, __HIP_MEMORY_SCOPE_AGENT);
                unsigned v3 = __hip_atomic_load(trow + 3, __ATOMIC_RELAXED, __HIP_MEMORY_SCOPE_AGENT);
                if ((v0 & v1 & v2 & v3) == 1u) break;
                __builtin_amdgcn_s_sleep(1);
            }
            if (lane == 0)
                __hip_atomic_store(&flagLDS, (unsigned)c, __ATOMIC_RELAXED, __HIP_MEMORY_SCOPE_WORKGROUP);
        } else if (w != 0) {
            unsigned need = m ? ((c >= 2) ? (unsigned)(c - 1) : 0u)
                             : (staticX ? 0u : (unsigned)c);
            if (need)
                while (__hip_atomic_load(&flagLDS, __ATOMIC_RELAXED,
                                         __HIP_MEMORY_SCOPE_WORKGROUP) < need)
                    __builtin_amdgcn_s_sleep(1);
        }
        asm volatile("" ::: "memory");

        // ---- A loads: this wave's disjoint 8KB chunk (4 kt x 2KB), fully coalesced
        const uchar* ap = asrc + (size_t)lane * 32;
        uint4 A[4][2];
#pragma unroll
        for (int t = 0; t < 4; ++t) {
            A[t][0] = *(const uint4*)(ap + (size_t)(q * 4 + t) * 2048);
            A[t][1] = *(const uint4*)(ap + (size_t)(q * 4 + t) * 2048 + 16);
        }
        const int mat = isL1 * 2 + m;
        const uchar* bp0 = wlds + (size_t)(mat * 2 + 0) * 16384 + lane * 16;
        const uchar* bp1 = wlds + (size_t)(mat * 2 + 1) * 16384 + lane * 16;
        const unsigned s0w = scw[mat][0], s1w = scw[mat][1];

        f32x4 a00 = {0.f,0.f,0.f,0.f}, a01 = {0.f,0.f,0.f,0.f};
        f32x4 a10 = {0.f,0.f,0.f,0.f}, a11 = {0.f,0.f,0.f,0.f};
#define MF(T, G)                                                                       \
        {                                                                              \
            uint4 alo = A[T][0], ahi = A[T][1];                                        \
            uint4 bb = *(const uint4*)(((G) ? bp1 : bp0) + (q * 4 + (T)) * 1024);      \
            i8v av = {(int)alo.x, (int)alo.y, (int)alo.z, (int)alo.w,                  \
                      (int)ahi.x, (int)ahi.y, (int)ahi.z, (int)ahi.w};                 \
            i8v bv = {(int)bb.x, (int)bb.y, (int)bb.z, (int)bb.w, 0, 0, 0, 0};         \
            f32x4& ac = (G) ? (((T) & 1) ? a11 : a10) : (((T) & 1) ? a01 : a00);       \
            ac = __builtin_amdgcn_mfma_scale_f32_16x16x128_f8f6f4(                     \
                av, bv, ac, 0, 4, 0, 127, T, (int)((G) ? s1w : s0w));                  \
        }
        MF(0, 0) MF(1, 0) MF(2, 0) MF(3, 0)
        MF(0, 1) MF(1, 1) MF(2, 1) MF(3, 1)
#undef MF
        f32x4 accJ0 = a00 + a01, accJ1 = a10 + a11;
#pragma unroll
        for (int i = 0; i < 4; ++i) {
            atomicAdd(&gbuf[par][0][kq * 4 + i][b16], accJ0[i]);
            atomicAdd(&gbuf[par][1][kq * 4 + i][b16], accJ1[i]);
        }

        if (pollAfter) {   // encode-L0: verify row c-1 after compute issue (hides under MFMA)
            const unsigned* trow = tags + (size_t)(c - 1) * 256 + lane * 4;
            for (;;) {
                unsigned v0 = __hip_atomic_load(trow + 0, __ATOMIC_RELAXED, __HIP_MEMORY_SCOPE_AGENT);
                unsigned v1 = __hip_atomic_load(trow + 1, __ATOMIC_RELAXED, __HIP_MEMORY_SCOPE_AGENT);
                unsigned v2 = __hip_atomic_load(trow + 2, __ATOMIC_RELAXED, __HIP_MEMORY_SCOPE_AGENT);
                unsigned v3 = __hip_atomic_load(trow + 3, __ATOMIC_RELAXED, __HIP_MEMORY_SCOPE_AGENT);
                if ((v0 & v1 & v2 & v3) == 1u) break;
                __builtin_amdgcn_s_sleep(1);
            }
            if (lane == 0)
                __hip_atomic_store(&flagLDS, (unsigned)c, __ATOMIC_RELAXED, __HIP_MEMORY_SCOPE_WORKGROUP);
        }
        __syncthreads();   // S1 — the only block-wide barrier per cell (drains ds atomics)

        if (w == 7) {
            const int b = lane >> 2, f0 = (lane & 3) * 2;
            u16 hb2 = 0;
            float hnv[2];
#pragma unroll
            for (int i = 0; i < 2; ++i) {
                const int f = f0 + i;
                float gv[4];
#pragma unroll
                for (int g = 0; g < 4; ++g) {
                    int gpp = g >> 1, jl = ((g & 1) << 3) | f;
                    gv[g] = gbuf[par][gpp][b][jl] * 0.25f + (isL1 ? bw1[i][g] : bw0[i][g]);
                }
                float co = isL1 ? cs1[i] : cs0[i];
                float cn = sigm(gv[1]) * co + sigm(gv[0]) * tanh_f(gv[2]);
                float hn = sigm(gv[3]) * tanh_f(cn);
                if (isL1) cs1[i] = cn; else cs0[i] = cn;
                hb2 |= (u16)(f2fp8(hn * 4.0f) << (8 * i));
                hnv[i] = hn;
            }
            // zero the consumed gbuf[par] entries (ready for reuse at cell c+2)
#pragma unroll
            for (int i = 0; i < 2; ++i) {
                const int f = f0 + i;
#pragma unroll
                for (int g = 0; g < 4; ++g)
                    gbuf[par][g >> 1][b][((g & 1) << 3) | f] = 0.f;
            }
            *(u16*)((uchar*)&hs_st[b]) ; // no-op guard (kept for clarity)
            *(u16*)((uchar*)&hs_st[b] + f0) = hb2;
            asm volatile("s_waitcnt lgkmcnt(0)" ::: "memory");
            if (lane < 16) {
                // fragment-layout publish: features bl*8..bl*8+7
                uchar* hdst = (isL1 ? H1 : H0) + (size_t)(s + 1) * BF;
                size_t o = (size_t)(bl >> 4) * 2048 + (size_t)((bl >> 2) & 3) * 512
                         + (size_t)(bl & 3) * 8 + (size_t)lane * 32;
                __hip_atomic_store((u64*)(hdst + o), hs_st[lane],
                                   __ATOMIC_RELAXED, __HIP_MEMORY_SCOPE_AGENT);
            }
            asm volatile("s_waitcnt vmcnt(0)" ::: "memory");   // h acked at L3
            if (lane == 0)
                __hip_atomic_store(tags + (size_t)c * 256 + bl, 1u,
                                   __ATOMIC_RELAXED, __HIP_MEMORY_SCOPE_AGENT);
            if (isL1 && s >= 31) {   // off the notify path (row-major bf16 for convout)
                unsigned pk = (unsigned)f2b(hnv[0]) | ((unsigned)f2b(hnv[1]) << 16);
                *(unsigned*)(seqout + (size_t)(s - 31) * BF + (size_t)b * FDIM + bl * 8 + f0) = pk;
            }
        }
    }
}

// ---------------- copy x into top half of output ----------------
__global__ void k_copyx(const float* __restrict__ x, float* __restrict__ out) {
    size_t n = (size_t)4096 * 256;
    size_t stride = (size_t)gridDim.x * blockDim.x;
    for (size_t i = (size_t)blockIdx.x * blockDim.x + threadIdx.x; i < n; i += stride) {
        size_t bc = i >> 8, r = i & 255;
        ((float4*)out)[bc * 512 + r] = ((const float4*)x)[i];
    }
}

// ---------------- output 1x1 conv into bottom half ----------------
__global__ __launch_bounds__(256) void k_convout(const u16* __restrict__ seqout,
                                                 const float* __restrict__ w_out,
                                                 const float* __restrict__ b_out,
                                                 float* __restrict__ out) {
    int s = blockIdx.x >> 4, b = blockIdx.x & 15;
    __shared__ float srow[2048];
    int tid = threadIdx.x;
    for (int i = tid; i < 2048; i += 256) srow[i] = b2f(seqout[((size_t)s * 16 + b) * FDIM + i]);
    __syncthreads();
    int o = tid;
    float bo = b_out[o];
    float wreg[64];
#pragma unroll
    for (int cb = 0; cb < 64; ++cb) wreg[cb] = w_out[o * 64 + cb];
    for (int w4 = 0; w4 < 8; ++w4) {
        float ac0 = bo, ac1 = bo, ac2 = bo, ac3 = bo;
#pragma unroll
        for (int cb = 0; cb < 64; ++cb) {
            float wv = wreg[cb];
            ac0 += srow[(w4 * 4 + 0) * 64 + cb] * wv;
            ac1 += srow[(w4 * 4 + 1) * 64 + cb] * wv;
            ac2 += srow[(w4 * 4 + 2) * 64 + cb] * wv;
            ac3 += srow[(w4 * 4 + 3) * 64 + cb] * wv;
        }
        float4 v; v.x = ac0; v.y = ac1; v.z = ac2; v.w = ac3;
        *(float4*)&out[(((size_t)b * 256 + o) * 64 + 32 + s) * 32 + w4 * 4] = v;
    }
}

extern "C" void kernel_launch(void* const* d_in, const int* in_sizes, int n_in,
                              void* d_out, int out_size, void* d_ws, size_t ws_size,
                              hipStream_t stream) {
    const float* x    = (const float*)d_in[0];
    const float* w_in = (const float*)d_in[1];
    const float* b_in = (const float*)d_in[2];
    const float* Wih0 = (const float*)d_in[3];
    const float* Whh0 = (const float*)d_in[4];
    const float* bih0 = (const float*)d_in[5];
    const float* bhh0 = (const float*)d_in[6];
    const float* Wih1 = (const float*)d_in[7];
    const float* Whh1 = (const float*)d_in[8];
    const float* bih1 = (const float*)d_in[9];
    const float* bhh1 = (const float*)d_in[10];
    const float* wout = (const float*)d_in[11];
    const float* bout = (const float*)d_in[12];
    float* out = (float*)d_out;
    char* ws = (char*)d_ws;
    const size_t BF = (size_t)16 * FDIM;

    uchar* Wp4 = (uchar*)ws;
    size_t off = (size_t)NBLK * 131072;                       // 32 MiB packed fp4 weights
    uchar* scl = (uchar*)(ws + off); off += (size_t)NBLK * 4 * 2 * 1024;   // 2 MiB scales
    float* bias0 = (float*)(ws + off); off += 4 * FDIM * 4;
    float* bias1 = (float*)(ws + off); off += 4 * FDIM * 4;
    uchar* seqb = (uchar*)(ws + off); off += (size_t)32 * BF;              // 1 MiB
    u16* seqout = (u16*)(ws + off); off += (size_t)32 * BF * 2;            // 2 MiB
    uchar* H0 = (uchar*)(ws + off); off += (size_t)64 * BF;                // 2 MiB (rotating slots)
    uchar* H1 = (uchar*)(ws + off); off += (size_t)64 * BF;                // 2 MiB
    off = (off + 127) & ~(size_t)127;
    unsigned* tags = (unsigned*)(ws + off); size_t tagoff = off;
    off += (size_t)NCELL * 256 * 4;                           // 126 KiB tag rows

    // zero: H0 slot0, H1 slot0, tag rows (in-graph, every replay)
    hipMemsetAsync(H0, 0, BF, stream);
    hipMemsetAsync(H1, 0, BF, stream);
    hipMemsetAsync(ws + tagoff, 0, off - tagoff, stream);

    k_pack4<<<256 * 4 * 16, 256, 0, stream>>>(Wih0, Whh0, Wih1, Whh1, Wp4, scl);
    k_bias<<<32, 256, 0, stream>>>(bih0, bhh0, bih1, bhh1, bias0, bias1);
    k_seqprep<<<512, 256, 0, stream>>>(x, w_in, b_in, seqb);
    k_lstm<<<NBLK, 512, 0, stream>>>(Wp4, scl, bias0, bias1, seqb, H0, H1, seqout, tags);
    k_copyx<<<2048, 256, 0, stream>>>(x, out);
    k_convout<<<512, 256, 0, stream>>>(seqout, wout, bout, out);
}